// Round 9
// baseline (203.562 us; speedup 1.0000x reference)
//
#include <hip/hip_runtime.h>

// CPRPackedLinear: out(64x11008) = xperm[:, :1024] @ deq6(W_high) + xperm[:, 1024:] @ deq5(W_low) + bias
//
// R9: R8 proved compaction alone buys little (gemm 48->~40us): the gemm's own
// structure (per-step barriers + ds_read_u8 dequant) is the remaining cost; its
// compute floor is ~5us. This version stores the compact weights FRAGMENT-MAJOR
// and PRE-UNPACKED: C2[gc=col/16][sg=k-step][lane]*8B, lane's 8 bytes = the 8
// already-unpacked values (6/5-bit weave done once in compact_w). The gemm W path
// is then one coalesced dwordx2 per lane per step, sequential across steps,
// straight to registers: NO LDS, NO barriers, uniform high/low code. A-fragments
// preloaded once per block (64KB LDS, one syncthreads), ds_read_b128 per MFMA.
// compact_w: block = (128 cols, one 32-k step): streaming-union row reads via
// LDS transpose, two 512-B contiguous write runs per wave.

#define NFEAT 11008
#define KTOT  4096

#define C2SIZE 45088768u    // 688 gc * 128 sg * 512 B

typedef _Float16     half8 __attribute__((ext_vector_type(8)));
typedef float        f32x4 __attribute__((ext_vector_type(4)));
typedef unsigned int u32x2 __attribute__((ext_vector_type(2)));
typedef unsigned int u32x4 __attribute__((ext_vector_type(4)));

#define GLOAD16(g, l) __builtin_amdgcn_global_load_lds(                         \
    (const __attribute__((address_space(1))) unsigned int*)(g),                 \
    (__attribute__((address_space(3))) unsigned int*)(l), 16, 0, 0)

// unpacked bytes v0..v7 -> fp16 (v - hr)*s  (mo = -hr*s)
#define DEQ8(w, s, mo, bf) do {                                                 \
    bf[0] = (_Float16)fmaf((float)((w)[0]         & 255u), (s), (mo));          \
    bf[1] = (_Float16)fmaf((float)(((w)[0] >>  8) & 255u), (s), (mo));          \
    bf[2] = (_Float16)fmaf((float)(((w)[0] >> 16) & 255u), (s), (mo));          \
    bf[3] = (_Float16)fmaf((float)( (w)[0] >> 24        ), (s), (mo));          \
    bf[4] = (_Float16)fmaf((float)((w)[1]         & 255u), (s), (mo));          \
    bf[5] = (_Float16)fmaf((float)(((w)[1] >>  8) & 255u), (s), (mo));          \
    bf[6] = (_Float16)fmaf((float)(((w)[1] >> 16) & 255u), (s), (mo));          \
    bf[7] = (_Float16)fmaf((float)( (w)[1] >> 24        ), (s), (mo));          \
} while (0)

// ---------------- prep: x_perm -> fp16 in MFMA A-fragment layout ----------------
// xfrag flat idx = ((s*4 + mt)*64 + lane)*8 + j
//   holds x[m = mt*16 + (lane&15)][ col_indices[k = s*32 + (lane>>4)*8 + j] ]
__global__ __launch_bounds__(256) void prep_xfrag(const float* __restrict__ x,
                                                  const int* __restrict__ col,
                                                  _Float16* __restrict__ xfrag) {
    int idx = blockIdx.x * 256 + threadIdx.x;          // 0..262143
    int j  = idx & 7;
    int l  = (idx >> 3) & 63;
    int mt = (idx >> 9) & 3;
    int s  = idx >> 11;
    int k  = s * 32 + ((l >> 4) << 3) + j;
    int m  = mt * 16 + (l & 15);
    xfrag[idx] = (_Float16)x[m * KTOT + col[k]];
}

// ---------------- compact: unpack 6/5-bit + fragment-major relayout ----------------
// grid (86, 128): y<32 -> high step s=y (24 rows); y>=32 -> low step s=y-32 (20 rows).
// Block reads its rows' 128-col span (512 B contiguous per row; 86 bx-blocks union
// a full row -> streaming). Writes: slot (gc_local, lane) = 8 unpacked bytes;
// each thread composes 2 slots -> one 16-B store; wave = 2x512-B contiguous runs.
__global__ __launch_bounds__(256) void compact_w(const int* __restrict__ Wh,
                                                 const int* __restrict__ Wl,
                                                 unsigned char* __restrict__ C2) {
    const int bx  = blockIdx.x;                        // 0..85
    const int y   = blockIdx.y;                        // 0..127
    const int tid = threadIdx.x;
    __shared__ unsigned char Lb[24][132];              // +4 pad: spread byte-read banks

    const bool high = (y < 32);
    const int  s    = high ? y : y - 32;
    const int  nrow = high ? 24 : 20;
    const int* src  = (high ? Wh + (size_t)(24 * s) * NFEAT
                            : Wl + (size_t)(20 * s) * NFEAT) + bx * 128;
    const int nint = nrow * 128;                       // 3072 / 2560
    for (int i = tid; i < nint; i += 256)
        Lb[i >> 7][i & 127] = (unsigned char)(src[(size_t)(i >> 7) * NFEAT + (i & 127)] & 255);
    __syncthreads();

    const int sg  = high ? s : 32 + s;                 // global k-step 0..127
    const int L   = (2 * tid) & 63;                    // slot lane (even)
    const int gcl = tid >> 5;                          // local 16-col group 0..7
    const int o   = L >> 4;                            // k-octet (same for L, L+1)

    unsigned int ow[4];
#pragma unroll
    for (int u = 0; u < 2; ++u) {
        const int c = gcl * 16 + ((L + u) & 15);
        unsigned int v0, v1, v2, v3, v4, v5, v6, v7;
        if (high) {
            const unsigned int b0 = Lb[6 * o + 0][c], b1 = Lb[6 * o + 1][c];
            const unsigned int b2 = Lb[6 * o + 2][c], b3 = Lb[6 * o + 3][c];
            const unsigned int b4 = Lb[6 * o + 4][c], b5 = Lb[6 * o + 5][c];
            v0 = b0 & 63;
            v1 = ((b0 >> 6) & 3) | ((b1 & 15) << 2);
            v2 = ((b1 >> 4) & 15) | ((b2 & 3) << 4);
            v3 = (b2 >> 2) & 63;
            v4 = b3 & 63;
            v5 = ((b3 >> 6) & 3) | ((b4 & 15) << 2);
            v6 = ((b4 >> 4) & 15) | ((b5 & 3) << 4);
            v7 = (b5 >> 2) & 63;
        } else {
            const unsigned int b0 = Lb[5 * o + 0][c], b1 = Lb[5 * o + 1][c];
            const unsigned int b2 = Lb[5 * o + 2][c], b3 = Lb[5 * o + 3][c];
            const unsigned int b4 = Lb[5 * o + 4][c];
            v0 = b0 & 31;
            v1 = ((b0 >> 5) & 7) | ((b1 & 3) << 3);
            v2 = (b1 >> 2) & 31;
            v3 = ((b1 >> 7) & 1) | ((b2 & 15) << 1);
            v4 = ((b2 >> 4) & 15) | ((b3 & 1) << 4);
            v5 = (b3 >> 1) & 31;
            v6 = ((b3 >> 6) & 3) | ((b4 & 7) << 2);
            v7 = (b4 >> 3) & 31;
        }
        ow[2 * u]     = v0 | (v1 << 8) | (v2 << 16) | (v3 << 24);
        ow[2 * u + 1] = v4 | (v5 << 8) | (v6 << 16) | (v7 << 24);
    }
    const size_t gc = (size_t)bx * 8 + gcl;
    u32x4* dp = (u32x4*)(C2 + (gc * 128 + sg) * 512 + L * 8);
    *dp = (u32x4){ow[0], ow[1], ow[2], ow[3]};
}

// ---------------- main GEMM (barrier-free W stream) ----------------
// grid (86, 8): 128-col tiles x 512-k chunks (kc 0..1 high, 2..7 low).
// block = 256 = 4 waves; wave w owns cols [n0+32w, +32) (2 gc), rows 0..63.
// A chunk (64 KB) preloaded to LDS once; W: 2 coalesced dwordx2/lane/step.
__global__ __launch_bounds__(256, 2) void gemm_kernel(const unsigned char* __restrict__ C2,
                                                      const float* __restrict__ sh,
                                                      const float* __restrict__ sl,
                                                      const _Float16* __restrict__ xfrag,
                                                      float* __restrict__ dst,
                                                      int atomic_mode) {
    const int bx   = blockIdx.x;
    const int kc   = blockIdx.y;
    const int lane = threadIdx.x & 63;
    const int wave = threadIdx.x >> 6;                  // 0..3
    const int ci   = lane & 15;
    const int n0   = bx * 128;

    __shared__ __align__(16) _Float16 Ald[32768];       // 16 steps x 4 mt x 1 KB

    // A preload: this kc-chunk's 64 KB of xfrag
    {
        const char* asrc = (const char*)xfrag + (size_t)kc * 65536;
        const char* ldst = (char*)Ald;
#pragma unroll
        for (int i = 0; i < 16; ++i)
            GLOAD16(asrc + ((size_t)threadIdx.x + i * 256) * 16,
                    ldst + ((size_t)threadIdx.x + i * 256) * 16);
    }

    // scales (latency overlaps the A-preload drain)
    const bool  high = (kc < 2);
    const float hr   = high ? 31.0f : 15.0f;
    float sc[4][2], mo[4][2];
#pragma unroll
    for (int g = 0; g < 4; ++g)
#pragma unroll
        for (int ng = 0; ng < 2; ++ng) {
            const int n = n0 + wave * 32 + ng * 16 + ci;
            const float s = high ? sh[(size_t)(kc * 4 + g) * NFEAT + n]
                                 : sl[(size_t)((kc - 2) * 4 + g) * NFEAT + n];
            sc[g][ng] = s;
            mo[g][ng] = -hr * s;
        }

    const size_t gc0 = (size_t)bx * 8 + wave * 2;
    const unsigned char* bW0 = C2 + ((gc0 + 0) * 128 + kc * 16) * 512 + lane * 8;
    const unsigned char* bW1 = C2 + ((gc0 + 1) * 128 + kc * 16) * 512 + lane * 8;

    f32x4 acc[4][2];
#pragma unroll
    for (int i = 0; i < 4; ++i)
#pragma unroll
        for (int j = 0; j < 2; ++j) acc[i][j] = (f32x4){0.f, 0.f, 0.f, 0.f};

    __syncthreads();                                    // A resident (drains vmcnt)

#pragma unroll
    for (int t = 0; t < 16; ++t) {
        const u32x2 w0 = *(const u32x2*)(bW0 + t * 512);
        const u32x2 w1 = *(const u32x2*)(bW1 + t * 512);
        const int g = t >> 2;
        half8 b0, b1;
        DEQ8(w0, sc[g][0], mo[g][0], b0);
        DEQ8(w1, sc[g][1], mo[g][1], b1);
#pragma unroll
        for (int mt = 0; mt < 4; ++mt) {
            half8 a = *(const half8*)&Ald[((t * 4 + mt) * 64 + lane) * 8];
            acc[mt][0] = __builtin_amdgcn_mfma_f32_16x16x32_f16(a, b0, acc[mt][0], 0, 0, 0);
            acc[mt][1] = __builtin_amdgcn_mfma_f32_16x16x32_f16(a, b1, acc[mt][1], 0, 0, 0);
        }
    }

    // ---- epilogue: waves own disjoint cols -> direct store ----
    const int r0 = (lane >> 4) << 2;
    if (atomic_mode) {
#pragma unroll
        for (int mt = 0; mt < 4; ++mt)
#pragma unroll
            for (int ng = 0; ng < 2; ++ng)
#pragma unroll
                for (int r = 0; r < 4; ++r)
                    atomicAdd(&dst[(size_t)(mt * 16 + r0 + r) * NFEAT + n0 + wave * 32 + ng * 16 + ci],
                              acc[mt][ng][r]);
    } else {
        float* base = dst + (size_t)kc * 64 * NFEAT;
#pragma unroll
        for (int mt = 0; mt < 4; ++mt)
#pragma unroll
            for (int ng = 0; ng < 2; ++ng)
#pragma unroll
                for (int r = 0; r < 4; ++r)
                    base[(size_t)(mt * 16 + r0 + r) * NFEAT + n0 + wave * 32 + ng * 16 + ci] = acc[mt][ng][r];
    }
}

// ---------------- tier-3 fallback: barrier-free direct gemm (verified in R4/R8) ----------------
__global__ __launch_bounds__(256, 4) void gemm_direct(const int* __restrict__ Wh,
                                                      const int* __restrict__ Wl,
                                                      const float* __restrict__ sh,
                                                      const float* __restrict__ sl,
                                                      const _Float16* __restrict__ xfrag,
                                                      float* __restrict__ dst) {
    const int n0   = blockIdx.x * 64;
    const int kc   = blockIdx.y;
    const int k0   = kc * 512;
    const int lane = threadIdx.x & 63;
    const int wave = threadIdx.x >> 6;
    const int n  = n0 + wave * 16 + (lane & 15);
    const int kb = (lane >> 4) << 3;

    f32x4 acc[4];
#pragma unroll
    for (int i = 0; i < 4; ++i) acc[i] = (f32x4){0.f, 0.f, 0.f, 0.f};

    if (k0 < 1024) {
        for (int g = 0; g < 4; ++g) {
            const float s    = sh[((k0 >> 7) + g) * NFEAT + n];
            const float moff = -31.0f * s;
#pragma unroll
            for (int st = 0; st < 4; ++st) {
                const int k = k0 + g * 128 + st * 32 + kb;
                const int* bp = Wh + 3 * (k >> 2) * NFEAT + n;
                const int b0 = bp[0];         const int b1 = bp[NFEAT];
                const int b2 = bp[2 * NFEAT]; const int b3 = bp[3 * NFEAT];
                const int b4 = bp[4 * NFEAT]; const int b5 = bp[5 * NFEAT];
                int v0 = b0 & 63;
                int v1 = ((b0 >> 6) & 3) | ((b1 & 15) << 2);
                int v2 = ((b1 >> 4) & 15) | ((b2 & 3) << 4);
                int v3 = (b2 >> 2) & 63;
                int v4 = b3 & 63;
                int v5 = ((b3 >> 6) & 3) | ((b4 & 15) << 2);
                int v6 = ((b4 >> 4) & 15) | ((b5 & 3) << 4);
                int v7 = (b5 >> 2) & 63;
                half8 b;
                b[0] = (_Float16)fmaf((float)v0, s, moff);
                b[1] = (_Float16)fmaf((float)v1, s, moff);
                b[2] = (_Float16)fmaf((float)v2, s, moff);
                b[3] = (_Float16)fmaf((float)v3, s, moff);
                b[4] = (_Float16)fmaf((float)v4, s, moff);
                b[5] = (_Float16)fmaf((float)v5, s, moff);
                b[6] = (_Float16)fmaf((float)v6, s, moff);
                b[7] = (_Float16)fmaf((float)v7, s, moff);
                const int sg = (k0 >> 5) + g * 4 + st;
#pragma unroll
                for (int mt = 0; mt < 4; ++mt) {
                    half8 a = *(const half8*)(xfrag + (((sg * 4 + mt) * 64 + lane) << 3));
                    acc[mt] = __builtin_amdgcn_mfma_f32_16x16x32_f16(a, b, acc[mt], 0, 0, 0);
                }
            }
        }
    } else {
        const int kl0 = k0 - 1024;
        for (int g = 0; g < 4; ++g) {
            const float s    = sl[((kl0 >> 7) + g) * NFEAT + n];
            const float moff = -15.0f * s;
#pragma unroll
            for (int st = 0; st < 4; ++st) {
                const int kl = kl0 + g * 128 + st * 32 + kb;
                const int* bp = Wl + 5 * (kl >> 3) * NFEAT + n;
                const int b0 = bp[0];         const int b1 = bp[NFEAT];
                const int b2 = bp[2 * NFEAT]; const int b3 = bp[3 * NFEAT];
                const int b4 = bp[4 * NFEAT];
                int v0 = b0 & 31;
                int v1 = ((b0 >> 5) & 7) | ((b1 & 3) << 3);
                int v2 = (b1 >> 2) & 31;
                int v3 = ((b1 >> 7) & 1) | ((b2 & 15) << 1);
                int v4 = ((b2 >> 4) & 15) | ((b3 & 1) << 4);
                int v5 = (b3 >> 1) & 31;
                int v6 = ((b3 >> 6) & 3) | ((b4 & 7) << 2);
                int v7 = (b4 >> 3) & 31;
                half8 b;
                b[0] = (_Float16)fmaf((float)v0, s, moff);
                b[1] = (_Float16)fmaf((float)v1, s, moff);
                b[2] = (_Float16)fmaf((float)v2, s, moff);
                b[3] = (_Float16)fmaf((float)v3, s, moff);
                b[4] = (_Float16)fmaf((float)v4, s, moff);
                b[5] = (_Float16)fmaf((float)v5, s, moff);
                b[6] = (_Float16)fmaf((float)v6, s, moff);
                b[7] = (_Float16)fmaf((float)v7, s, moff);
                const int sg = 32 + (kl0 >> 5) + g * 4 + st;
#pragma unroll
                for (int mt = 0; mt < 4; ++mt) {
                    half8 a = *(const half8*)(xfrag + (((sg * 4 + mt) * 64 + lane) << 3));
                    acc[mt] = __builtin_amdgcn_mfma_f32_16x16x32_f16(a, b, acc[mt], 0, 0, 0);
                }
            }
        }
    }

    const int r0 = (lane >> 4) << 2;
#pragma unroll
    for (int mt = 0; mt < 4; ++mt)
#pragma unroll
        for (int r = 0; r < 4; ++r)
            atomicAdd(&dst[(mt * 16 + r0 + r) * NFEAT + n], acc[mt][r]);
}

// ---------------- reduce: out = bias + sum_kc partial[kc] ----------------
__global__ __launch_bounds__(256) void reduce_out(const float* __restrict__ part,
                                                  const float* __restrict__ bias,
                                                  float* __restrict__ out, int nc) {
    const int idx = blockIdx.x * 256 + threadIdx.x;    // 0..176127 (float4 units)
    const int f   = idx * 4;
    const int n   = f % NFEAT;                          // NFEAT % 4 == 0 -> same row
    f32x4 sum = *(const f32x4*)(bias + n);
    for (int c = 0; c < nc; ++c)
        sum += *(const f32x4*)(part + (size_t)c * 704512 + f);
    *(f32x4*)(out + f) = sum;
}

__global__ __launch_bounds__(256) void init_bias(const float* __restrict__ bias,
                                                 float* __restrict__ out) {
    const int idx = blockIdx.x * 256 + threadIdx.x;    // 0..704511
    out[idx] = bias[idx % NFEAT];
}

extern "C" void kernel_launch(void* const* d_in, const int* in_sizes, int n_in,
                              void* d_out, int out_size, void* d_ws, size_t ws_size,
                              hipStream_t stream) {
    const float* x    = (const float*)d_in[0];
    const int*   Wh   = (const int*)d_in[1];
    const int*   Wl   = (const int*)d_in[2];
    const float* sh   = (const float*)d_in[3];
    const float* sl   = (const float*)d_in[4];
    const int*   col  = (const int*)d_in[5];
    const float* bias = (const float*)d_in[6];
    float* out = (float*)d_out;

    _Float16* xfrag = (_Float16*)d_ws;                 // 512 KB
    const size_t xo = 524288;
    const size_t part_bytes = 8ull * 64 * NFEAT * sizeof(float);   // 22,544,384

    prep_xfrag<<<1024, 256, 0, stream>>>(x, col, xfrag);

    if (ws_size >= xo + part_bytes + C2SIZE) {
        // tier 1: compact + partials + reduce
        float*         part = (float*)((char*)d_ws + xo);
        unsigned char* C2   = (unsigned char*)d_ws + xo + part_bytes;
        compact_w<<<dim3(86, 128), 256, 0, stream>>>(Wh, Wl, C2);
        gemm_kernel<<<dim3(86, 8), 256, 0, stream>>>(C2, sh, sl, xfrag, part, 0);
        reduce_out<<<688, 256, 0, stream>>>(part, bias, out, 8);
    } else if (ws_size >= xo + C2SIZE) {
        // tier 2: compact + atomic accumulate into out
        unsigned char* C2 = (unsigned char*)d_ws + xo;
        compact_w<<<dim3(86, 128), 256, 0, stream>>>(Wh, Wl, C2);
        init_bias<<<2752, 256, 0, stream>>>(bias, out);
        gemm_kernel<<<dim3(86, 8), 256, 0, stream>>>(C2, sh, sl, xfrag, out, 1);
    } else {
        // tier 3: no room for C2 -> direct-read gemm
        init_bias<<<2752, 256, 0, stream>>>(bias, out);
        gemm_direct<<<dim3(172, 8), 256, 0, stream>>>(Wh, Wl, sh, sl, xfrag, out);
    }
}

// Round 10
// 200.953 us; speedup vs baseline: 1.0130x; 1.0130x over previous
//
#include <hip/hip_runtime.h>

// CPRPackedLinear: out(64x11008) = xperm[:, :1024] @ deq6(W_high) + xperm[:, 1024:] @ deq5(W_low) + bias
//
// R10: session-wide invariant identified: ANY read pattern built from <=512-B
// spans at multi-KB stride runs at 1-2.4 TB/s (R0-R6 gemms, R9 compact 1.75,
// R9 gemm 2.3); the only 6.8 TB/s dispatch is the harness's SEQUENTIAL fill.
// This round makes every heavy reader sequential:
//   strip_low:  thread-linear stream of Wh/Wl -> 29.6 MB low-byte array WB.
//               (Also the decisive probe: if THIS runs at 2 TB/s, reads are
//               capped and R5 was the roofline.)
//   transpose_w: R9's verified weave, reading WB (L3-resident, 4x fewer bytes),
//               writing C3 re-blocked so each gemm wave's K-loop is ONE
//               contiguous 16-KB region.
//   gemm:       R9's verified math; no LDS; W-read walks 1-KB steps
//               sequentially; (256,4) -> 16 waves/CU.

#define NFEAT 11008
#define KTOT  4096

#define WBH_BYTES 8454144u          // 768 rows  * 11008
#define WB_BYTES  29589504u         // + 1920 rows * 11008
#define C3_BYTES  45088768u         // 86 bx * 4 w * 8 kc * 16 t * 1024

typedef _Float16     half8 __attribute__((ext_vector_type(8)));
typedef float        f32x4 __attribute__((ext_vector_type(4)));
typedef unsigned int u32x2 __attribute__((ext_vector_type(2)));
typedef unsigned int u32x4 __attribute__((ext_vector_type(4)));

// unpacked bytes v0..v7 -> fp16 (v - hr)*s  (mo = -hr*s)
#define DEQ8(w, s, mo, bf) do {                                                 \
    bf[0] = (_Float16)fmaf((float)((w)[0]         & 255u), (s), (mo));          \
    bf[1] = (_Float16)fmaf((float)(((w)[0] >>  8) & 255u), (s), (mo));          \
    bf[2] = (_Float16)fmaf((float)(((w)[0] >> 16) & 255u), (s), (mo));          \
    bf[3] = (_Float16)fmaf((float)( (w)[0] >> 24        ), (s), (mo));          \
    bf[4] = (_Float16)fmaf((float)((w)[1]         & 255u), (s), (mo));          \
    bf[5] = (_Float16)fmaf((float)(((w)[1] >>  8) & 255u), (s), (mo));          \
    bf[6] = (_Float16)fmaf((float)(((w)[1] >> 16) & 255u), (s), (mo));          \
    bf[7] = (_Float16)fmaf((float)( (w)[1] >> 24        ), (s), (mo));          \
} while (0)

// ---------------- prep: x_perm -> fp16 in MFMA A-fragment layout ----------------
__global__ __launch_bounds__(256) void prep_xfrag(const float* __restrict__ x,
                                                  const int* __restrict__ col,
                                                  _Float16* __restrict__ xfrag) {
    int idx = blockIdx.x * 256 + threadIdx.x;          // 0..262143
    int j  = idx & 7;
    int l  = (idx >> 3) & 63;
    int mt = (idx >> 9) & 3;
    int s  = idx >> 11;
    int k  = s * 32 + ((l >> 4) << 3) + j;
    int m  = mt * 16 + (l & 15);
    xfrag[idx] = (_Float16)x[m * KTOT + col[k]];
}

// ---------------- stage A: sequential low-byte strip ----------------
// unit = 4 ints (16-B load, 4-B store). Wave: 1-KB coalesced sequential reads.
// WB = low bytes of Wh (row-major) then Wl (row-major).
__global__ __launch_bounds__(256) void strip_low(const int* __restrict__ Wh,
                                                 const int* __restrict__ Wl,
                                                 unsigned int* __restrict__ WB4) {
    const unsigned int u = blockIdx.x * 256 + threadIdx.x;   // 0..7397375
    const int* s = (u < 2113536u) ? Wh + (size_t)u * 4
                                  : Wl + ((size_t)u - 2113536u) * 4;
    u32x4 v = *(const u32x4*)s;
    WB4[u] = (v[0] & 255u) | ((v[1] & 255u) << 8) |
             ((v[2] & 255u) << 16) | ((v[3] & 255u) << 24);
}

// ---------------- stage B: weave + fragment-major relayout (R9 logic) ----------------
// grid (86, 128): y<32 -> high step s=y (24 rows); else low step s=y-32 (20 rows).
// Reads WB rows' 128-B spans (L3-resident). Writes C3 wave-sequential layout:
// slot (bx, gcl, sg): w=gcl>>1, half=gcl&1, kc=sg>>4, t=sg&15:
//   C3[ ((((bx*4+w)*8+kc)*16+t) * 1024 + half*512 + L*8 ]
__global__ __launch_bounds__(256) void transpose_w(const unsigned char* __restrict__ WB,
                                                   unsigned char* __restrict__ C3) {
    const int bx  = blockIdx.x;                        // 0..85
    const int y   = blockIdx.y;                        // 0..127
    const int tid = threadIdx.x;
    __shared__ __align__(16) unsigned char Lbyte[24 * 144];   // row stride 144 (16-mult)

    const bool high = (y < 32);
    const int  s    = high ? y : y - 32;
    const int  nrow = high ? 24 : 20;
    const unsigned char* src = WB + (high ? 0u : WBH_BYTES)
                             + (size_t)(nrow * s) * NFEAT + bx * 128;
    const int nchunk = nrow * 8;                       // 16-B chunks (192 / 160)
    if (tid < nchunk) {
        const int row = tid >> 3, ch = tid & 7;
        *(u32x4*)&Lbyte[row * 144 + ch * 16] =
            *(const u32x4*)(src + (size_t)row * NFEAT + ch * 16);
    }
    __syncthreads();

    const int sg  = high ? s : 32 + s;                 // global 32-k step 0..127
    const int L   = (2 * tid) & 63;                    // even slot lane
    const int gcl = tid >> 5;                          // local 16-col group 0..7
    const int o   = L >> 4;                            // k-octet (same for L, L+1)

    unsigned int ow[4];
#pragma unroll
    for (int u = 0; u < 2; ++u) {
        const int c = gcl * 16 + ((L + u) & 15);
        unsigned int v0, v1, v2, v3, v4, v5, v6, v7;
        if (high) {
            const unsigned int b0 = Lbyte[(6 * o + 0) * 144 + c];
            const unsigned int b1 = Lbyte[(6 * o + 1) * 144 + c];
            const unsigned int b2 = Lbyte[(6 * o + 2) * 144 + c];
            const unsigned int b3 = Lbyte[(6 * o + 3) * 144 + c];
            const unsigned int b4 = Lbyte[(6 * o + 4) * 144 + c];
            const unsigned int b5 = Lbyte[(6 * o + 5) * 144 + c];
            v0 = b0 & 63;
            v1 = ((b0 >> 6) & 3) | ((b1 & 15) << 2);
            v2 = ((b1 >> 4) & 15) | ((b2 & 3) << 4);
            v3 = (b2 >> 2) & 63;
            v4 = b3 & 63;
            v5 = ((b3 >> 6) & 3) | ((b4 & 15) << 2);
            v6 = ((b4 >> 4) & 15) | ((b5 & 3) << 4);
            v7 = (b5 >> 2) & 63;
        } else {
            const unsigned int b0 = Lbyte[(5 * o + 0) * 144 + c];
            const unsigned int b1 = Lbyte[(5 * o + 1) * 144 + c];
            const unsigned int b2 = Lbyte[(5 * o + 2) * 144 + c];
            const unsigned int b3 = Lbyte[(5 * o + 3) * 144 + c];
            const unsigned int b4 = Lbyte[(5 * o + 4) * 144 + c];
            v0 = b0 & 31;
            v1 = ((b0 >> 5) & 7) | ((b1 & 3) << 3);
            v2 = (b1 >> 2) & 31;
            v3 = ((b1 >> 7) & 1) | ((b2 & 15) << 1);
            v4 = ((b2 >> 4) & 15) | ((b3 & 1) << 4);
            v5 = (b3 >> 1) & 31;
            v6 = ((b3 >> 6) & 3) | ((b4 & 7) << 2);
            v7 = (b4 >> 3) & 31;
        }
        ow[2 * u]     = v0 | (v1 << 8) | (v2 << 16) | (v3 << 24);
        ow[2 * u + 1] = v4 | (v5 << 8) | (v6 << 16) | (v7 << 24);
    }
    const int w = gcl >> 1, half = gcl & 1;
    const int kc = sg >> 4, t = sg & 15;
    u32x4* dp = (u32x4*)(C3 + ((((size_t)bx * 4 + w) * 8 + kc) * 16 + t) * 1024
                            + half * 512 + L * 8);
    *dp = (u32x4){ow[0], ow[1], ow[2], ow[3]};
}

// ---------------- main GEMM (no LDS; wave-sequential W stream) ----------------
// grid (86, 8); 256 thr = 4 waves; wave w owns cols [bx*128+32w, +32), rows 0..63.
// W: per step ONE contiguous 1-KB wave read; 16 steps walk a contiguous 16 KB.
__global__ __launch_bounds__(256, 4) void gemm_kernel(const unsigned char* __restrict__ C3,
                                                      const float* __restrict__ sh,
                                                      const float* __restrict__ sl,
                                                      const _Float16* __restrict__ xfrag,
                                                      float* __restrict__ dst,
                                                      int atomic_mode) {
    const int bx   = blockIdx.x;
    const int kc   = blockIdx.y;
    const int lane = threadIdx.x & 63;
    const int wave = threadIdx.x >> 6;                  // 0..3
    const int ci   = lane & 15;
    const int n0   = bx * 128;

    const bool  high = (kc < 2);
    const float hr   = high ? 31.0f : 15.0f;
    float sc[4][2], mo[4][2];
#pragma unroll
    for (int g = 0; g < 4; ++g)
#pragma unroll
        for (int ng = 0; ng < 2; ++ng) {
            const int n = n0 + wave * 32 + ng * 16 + ci;
            const float s = high ? sh[(size_t)(kc * 4 + g) * NFEAT + n]
                                 : sl[(size_t)((kc - 2) * 4 + g) * NFEAT + n];
            sc[g][ng] = s;
            mo[g][ng] = -hr * s;
        }

    const unsigned char* pw = C3 + ((((size_t)bx * 4 + wave) * 8 + kc) << 14) + lane * 8;

    f32x4 acc[4][2];
#pragma unroll
    for (int i = 0; i < 4; ++i)
#pragma unroll
        for (int j = 0; j < 2; ++j) acc[i][j] = (f32x4){0.f, 0.f, 0.f, 0.f};

#pragma unroll
    for (int t = 0; t < 16; ++t) {
        const u32x2 w0 = *(const u32x2*)(pw + t * 1024);
        const u32x2 w1 = *(const u32x2*)(pw + t * 1024 + 512);
        const int g = t >> 2;
        half8 b0, b1;
        DEQ8(w0, sc[g][0], mo[g][0], b0);
        DEQ8(w1, sc[g][1], mo[g][1], b1);
#pragma unroll
        for (int mt = 0; mt < 4; ++mt) {
            half8 a = *(const half8*)(xfrag +
                (((size_t)((kc * 16 + t) * 4 + mt) * 64 + lane) << 3));
            acc[mt][0] = __builtin_amdgcn_mfma_f32_16x16x32_f16(a, b0, acc[mt][0], 0, 0, 0);
            acc[mt][1] = __builtin_amdgcn_mfma_f32_16x16x32_f16(a, b1, acc[mt][1], 0, 0, 0);
        }
    }

    // ---- epilogue: waves own disjoint cols -> direct store ----
    const int r0 = (lane >> 4) << 2;
    if (atomic_mode) {
#pragma unroll
        for (int mt = 0; mt < 4; ++mt)
#pragma unroll
            for (int ng = 0; ng < 2; ++ng)
#pragma unroll
                for (int r = 0; r < 4; ++r)
                    atomicAdd(&dst[(size_t)(mt * 16 + r0 + r) * NFEAT + n0 + wave * 32 + ng * 16 + ci],
                              acc[mt][ng][r]);
    } else {
        float* base = dst + (size_t)kc * 64 * NFEAT;
#pragma unroll
        for (int mt = 0; mt < 4; ++mt)
#pragma unroll
            for (int ng = 0; ng < 2; ++ng)
#pragma unroll
                for (int r = 0; r < 4; ++r)
                    base[(size_t)(mt * 16 + r0 + r) * NFEAT + n0 + wave * 32 + ng * 16 + ci] = acc[mt][ng][r];
    }
}

// ---------------- tier-3 fallback: barrier-free direct gemm (verified R4/R8) ----------------
__global__ __launch_bounds__(256, 4) void gemm_direct(const int* __restrict__ Wh,
                                                      const int* __restrict__ Wl,
                                                      const float* __restrict__ sh,
                                                      const float* __restrict__ sl,
                                                      const _Float16* __restrict__ xfrag,
                                                      float* __restrict__ dst) {
    const int n0   = blockIdx.x * 64;
    const int kc   = blockIdx.y;
    const int k0   = kc * 512;
    const int lane = threadIdx.x & 63;
    const int wave = threadIdx.x >> 6;
    const int n  = n0 + wave * 16 + (lane & 15);
    const int kb = (lane >> 4) << 3;

    f32x4 acc[4];
#pragma unroll
    for (int i = 0; i < 4; ++i) acc[i] = (f32x4){0.f, 0.f, 0.f, 0.f};

    if (k0 < 1024) {
        for (int g = 0; g < 4; ++g) {
            const float s    = sh[((k0 >> 7) + g) * NFEAT + n];
            const float moff = -31.0f * s;
#pragma unroll
            for (int st = 0; st < 4; ++st) {
                const int k = k0 + g * 128 + st * 32 + kb;
                const int* bp = Wh + 3 * (k >> 2) * NFEAT + n;
                const int b0 = bp[0];         const int b1 = bp[NFEAT];
                const int b2 = bp[2 * NFEAT]; const int b3 = bp[3 * NFEAT];
                const int b4 = bp[4 * NFEAT]; const int b5 = bp[5 * NFEAT];
                int v0 = b0 & 63;
                int v1 = ((b0 >> 6) & 3) | ((b1 & 15) << 2);
                int v2 = ((b1 >> 4) & 15) | ((b2 & 3) << 4);
                int v3 = (b2 >> 2) & 63;
                int v4 = b3 & 63;
                int v5 = ((b3 >> 6) & 3) | ((b4 & 15) << 2);
                int v6 = ((b4 >> 4) & 15) | ((b5 & 3) << 4);
                int v7 = (b5 >> 2) & 63;
                half8 b;
                b[0] = (_Float16)fmaf((float)v0, s, moff);
                b[1] = (_Float16)fmaf((float)v1, s, moff);
                b[2] = (_Float16)fmaf((float)v2, s, moff);
                b[3] = (_Float16)fmaf((float)v3, s, moff);
                b[4] = (_Float16)fmaf((float)v4, s, moff);
                b[5] = (_Float16)fmaf((float)v5, s, moff);
                b[6] = (_Float16)fmaf((float)v6, s, moff);
                b[7] = (_Float16)fmaf((float)v7, s, moff);
                const int sg = (k0 >> 5) + g * 4 + st;
#pragma unroll
                for (int mt = 0; mt < 4; ++mt) {
                    half8 a = *(const half8*)(xfrag + (((sg * 4 + mt) * 64 + lane) << 3));
                    acc[mt] = __builtin_amdgcn_mfma_f32_16x16x32_f16(a, b, acc[mt], 0, 0, 0);
                }
            }
        }
    } else {
        const int kl0 = k0 - 1024;
        for (int g = 0; g < 4; ++g) {
            const float s    = sl[((kl0 >> 7) + g) * NFEAT + n];
            const float moff = -15.0f * s;
#pragma unroll
            for (int st = 0; st < 4; ++st) {
                const int kl = kl0 + g * 128 + st * 32 + kb;
                const int* bp = Wl + 5 * (kl >> 3) * NFEAT + n;
                const int b0 = bp[0];         const int b1 = bp[NFEAT];
                const int b2 = bp[2 * NFEAT]; const int b3 = bp[3 * NFEAT];
                const int b4 = bp[4 * NFEAT];
                int v0 = b0 & 31;
                int v1 = ((b0 >> 5) & 7) | ((b1 & 3) << 3);
                int v2 = (b1 >> 2) & 31;
                int v3 = ((b1 >> 7) & 1) | ((b2 & 15) << 1);
                int v4 = ((b2 >> 4) & 15) | ((b3 & 1) << 4);
                int v5 = (b3 >> 1) & 31;
                int v6 = ((b3 >> 6) & 3) | ((b4 & 7) << 2);
                int v7 = (b4 >> 3) & 31;
                half8 b;
                b[0] = (_Float16)fmaf((float)v0, s, moff);
                b[1] = (_Float16)fmaf((float)v1, s, moff);
                b[2] = (_Float16)fmaf((float)v2, s, moff);
                b[3] = (_Float16)fmaf((float)v3, s, moff);
                b[4] = (_Float16)fmaf((float)v4, s, moff);
                b[5] = (_Float16)fmaf((float)v5, s, moff);
                b[6] = (_Float16)fmaf((float)v6, s, moff);
                b[7] = (_Float16)fmaf((float)v7, s, moff);
                const int sg = 32 + (kl0 >> 5) + g * 4 + st;
#pragma unroll
                for (int mt = 0; mt < 4; ++mt) {
                    half8 a = *(const half8*)(xfrag + (((sg * 4 + mt) * 64 + lane) << 3));
                    acc[mt] = __builtin_amdgcn_mfma_f32_16x16x32_f16(a, b, acc[mt], 0, 0, 0);
                }
            }
        }
    }

    const int r0 = (lane >> 4) << 2;
#pragma unroll
    for (int mt = 0; mt < 4; ++mt)
#pragma unroll
        for (int r = 0; r < 4; ++r)
            atomicAdd(&dst[(mt * 16 + r0 + r) * NFEAT + n], acc[mt][r]);
}

// ---------------- reduce: out = bias + sum_kc partial[kc] ----------------
__global__ __launch_bounds__(256) void reduce_out(const float* __restrict__ part,
                                                  const float* __restrict__ bias,
                                                  float* __restrict__ out, int nc) {
    const int idx = blockIdx.x * 256 + threadIdx.x;    // 0..176127 (float4 units)
    const int f   = idx * 4;
    const int n   = f % NFEAT;
    f32x4 sum = *(const f32x4*)(bias + n);
    for (int c = 0; c < nc; ++c)
        sum += *(const f32x4*)(part + (size_t)c * 704512 + f);
    *(f32x4*)(out + f) = sum;
}

__global__ __launch_bounds__(256) void init_bias(const float* __restrict__ bias,
                                                 float* __restrict__ out) {
    const int idx = blockIdx.x * 256 + threadIdx.x;    // 0..704511
    out[idx] = bias[idx % NFEAT];
}

extern "C" void kernel_launch(void* const* d_in, const int* in_sizes, int n_in,
                              void* d_out, int out_size, void* d_ws, size_t ws_size,
                              hipStream_t stream) {
    const float* x    = (const float*)d_in[0];
    const int*   Wh   = (const int*)d_in[1];
    const int*   Wl   = (const int*)d_in[2];
    const float* sh   = (const float*)d_in[3];
    const float* sl   = (const float*)d_in[4];
    const int*   col  = (const int*)d_in[5];
    const float* bias = (const float*)d_in[6];
    float* out = (float*)d_out;

    _Float16* xfrag = (_Float16*)d_ws;                 // 512 KB
    const size_t xo         = 524288;
    const size_t part_bytes = 8ull * 64 * NFEAT * sizeof(float);   // 22,544,384

    prep_xfrag<<<1024, 256, 0, stream>>>(x, col, xfrag);

    if (ws_size >= xo + part_bytes + WB_BYTES + C3_BYTES) {
        // tier 1: strip -> transpose -> gemm(partials) -> reduce
        float*         part = (float*)((char*)d_ws + xo);
        unsigned char* WB   = (unsigned char*)d_ws + xo + part_bytes;
        unsigned char* C3   = WB + WB_BYTES;
        strip_low<<<28896, 256, 0, stream>>>(Wh, Wl, (unsigned int*)WB);
        transpose_w<<<dim3(86, 128), 256, 0, stream>>>(WB, C3);
        gemm_kernel<<<dim3(86, 8), 256, 0, stream>>>(C3, sh, sl, xfrag, part, 0);
        reduce_out<<<688, 256, 0, stream>>>(part, bias, out, 8);
    } else if (ws_size >= xo + WB_BYTES + C3_BYTES) {
        // tier 2: strip -> transpose -> gemm(atomic into out)
        unsigned char* WB = (unsigned char*)d_ws + xo;
        unsigned char* C3 = WB + WB_BYTES;
        strip_low<<<28896, 256, 0, stream>>>(Wh, Wl, (unsigned int*)WB);
        transpose_w<<<dim3(86, 128), 256, 0, stream>>>(WB, C3);
        init_bias<<<2752, 256, 0, stream>>>(bias, out);
        gemm_kernel<<<dim3(86, 8), 256, 0, stream>>>(C3, sh, sl, xfrag, out, 1);
    } else {
        // tier 3: direct-read gemm
        init_bias<<<2752, 256, 0, stream>>>(bias, out);
        gemm_direct<<<dim3(172, 8), 256, 0, stream>>>(Wh, Wl, sh, sl, xfrag, out);
    }
}

// Round 11
// 169.878 us; speedup vs baseline: 1.1983x; 1.1829x over previous
//
#include <hip/hip_runtime.h>

// CPRPackedLinear: out(64x11008) = xperm[:, :1024] @ deq6(W_high) + xperm[:, 1024:] @ deq5(W_low) + bias
//
// R11 = REVERT to R5 (best measured: 173.0 us total, gemm ~48 us).
// Session conclusion: the read-path service rate for this problem's buffers is
// ~2.4 TB/s regardless of pattern (scattered 4B spans, 512B spans, fully
// sequential 16B/lane streams all measured ~2.4; the 6.7 TB/s reference is a
// WRITE-only fill). Floor for any algorithm = 118.35 MB weights / 2.4 TB/s
// ~= 49 us. This single-pass kernel sits on that floor; all multi-pass
// variants (R8/R9/R10: 190/204/201) pay the cap once per pass and lose.
// Structure: global_load_lds staging (zero register cost per in-flight load),
// 4-buffer rotation, counted s_waitcnt vmcnt(14/12) never drained to 0
// mid-loop, raw s_barrier per step, waves own disjoint 16-col strips.

#define NFEAT 11008
#define KTOT  4096

typedef _Float16 half8 __attribute__((ext_vector_type(8)));
typedef float    f32x4 __attribute__((ext_vector_type(4)));

#define GLOAD4(g, l)  __builtin_amdgcn_global_load_lds(                         \
    (const __attribute__((address_space(1))) unsigned int*)(g),                 \
    (__attribute__((address_space(3))) unsigned int*)(l), 4, 0, 0)
#define GLOAD16(g, l) __builtin_amdgcn_global_load_lds(                         \
    (const __attribute__((address_space(1))) unsigned int*)(g),                 \
    (__attribute__((address_space(3))) unsigned int*)(l), 16, 0, 0)
#define WAITV(N) asm volatile("s_waitcnt vmcnt(" #N ")" ::: "memory")

// ---------------- prep: x_perm -> fp16 in MFMA A-fragment layout ----------------
// xfrag flat idx = ((s*4 + mt)*64 + lane)*8 + j
//   holds x[m = mt*16 + (lane&15)][ col_indices[k = s*32 + (lane>>4)*8 + j] ]
__global__ __launch_bounds__(256) void prep_xfrag(const float* __restrict__ x,
                                                  const int* __restrict__ col,
                                                  _Float16* __restrict__ xfrag) {
    int idx = blockIdx.x * 256 + threadIdx.x;          // 0..262143
    int j  = idx & 7;
    int l  = (idx >> 3) & 63;
    int mt = (idx >> 9) & 3;
    int s  = idx >> 11;
    int k  = s * 32 + ((l >> 4) << 3) + j;
    int m  = mt * 16 + (l & 15);
    xfrag[idx] = (_Float16)x[m * KTOT + col[k]];
}

// ---------------- main GEMM ----------------
// grid = (172, 4): 64-col tiles x 1024-k chunks (kc0 = 6-bit, kc1..3 = 5-bit).
// block = 256 = 4 waves. Wave w owns cols [n0+16w, n0+16w+16), rows 0..63.
// Per 32-k step: stage 24 (6b) / 20 (5b) packed rows + 4 A-frags into LDS via
// global_load_lds; each lane dequants its k-octet straight into the MFMA B-frag.
__global__ __launch_bounds__(256, 3) void gemm_kernel(const int* __restrict__ Wh,
                                                      const int* __restrict__ Wl,
                                                      const float* __restrict__ sh,
                                                      const float* __restrict__ sl,
                                                      const _Float16* __restrict__ xfrag,
                                                      float* __restrict__ dst,
                                                      int atomic_mode) {
    const int n0   = blockIdx.x * 64;
    const int kc   = blockIdx.y;
    const int lane = threadIdx.x & 63;
    const int wave = threadIdx.x >> 6;                  // 0..3
    const int cb   = wave * 16 + (lane & 15);           // block-local col 0..63
    const int n    = n0 + cb;                           // global output column
    const int o    = lane >> 4;                         // k-octet 0..3

    // W rows: stride 68 ints (6-bit, 24 rows) or 72 ints (5-bit, 20 rows);
    // 16B/32B pad rotates banks so the 4 octet-groups' reads are <=2-way.
    __shared__ int Wb[4][1632];                         // 4 bufs x 6528 B
    __shared__ __align__(16) _Float16 Ab[4][4][512];    // 4 bufs x 4 mt x 1 KB

    f32x4 acc[4];
#pragma unroll
    for (int i = 0; i < 4; ++i) acc[i] = (f32x4){0.f, 0.f, 0.f, 0.f};

    if (kc == 0) {
        // ================= 6-bit region (k 0..1024, 32 steps) =================
        float sc[8];
#pragma unroll
        for (int g = 0; g < 8; ++g) sc[g] = sh[g * NFEAT + n];   // statically indexed

#define STAGE6(T) do {                                                         \
        const int _t = (T); const int _b = _t & 3;                             \
        const int* _gs = Wh + (_t * 24 + wave * 6) * NFEAT + n0 + lane;        \
        GLOAD4(_gs,             &Wb[_b][(wave * 6 + 0) * 68]);                 \
        GLOAD4(_gs + 1 * NFEAT, &Wb[_b][(wave * 6 + 1) * 68]);                 \
        GLOAD4(_gs + 2 * NFEAT, &Wb[_b][(wave * 6 + 2) * 68]);                 \
        GLOAD4(_gs + 3 * NFEAT, &Wb[_b][(wave * 6 + 3) * 68]);                 \
        GLOAD4(_gs + 4 * NFEAT, &Wb[_b][(wave * 6 + 4) * 68]);                 \
        GLOAD4(_gs + 5 * NFEAT, &Wb[_b][(wave * 6 + 5) * 68]);                 \
        GLOAD16(xfrag + ((size_t)(_t * 4 + wave) * 64 + lane) * 8,             \
                &Ab[_b][wave][0]);                                             \
    } while (0)

        STAGE6(0);
        STAGE6(1);
#pragma unroll
        for (int g = 0; g < 8; ++g) {
            for (int st = 0; st < 4; ++st) {
                const int t = g * 4 + st;
                if (t + 2 < 32) { STAGE6(t + 2); WAITV(14); }   // 2 batches x 7 in flight
                else if (t + 1 < 32) { WAITV(7); }
                else { WAITV(0); }
                __builtin_amdgcn_s_barrier();
                asm volatile("" ::: "memory");

                const int  bi = t & 3;
                const int* wr = &Wb[bi][(o * 6) * 68 + cb];
                const int b0 = wr[0];      const int b1 = wr[68];
                const int b2 = wr[2 * 68]; const int b3 = wr[3 * 68];
                const int b4 = wr[4 * 68]; const int b5 = wr[5 * 68];
                int v0 = b0 & 63;
                int v1 = ((b0 >> 6) & 3) | ((b1 & 15) << 2);
                int v2 = ((b1 >> 4) & 15) | ((b2 & 3) << 4);
                int v3 = (b2 >> 2) & 63;
                int v4 = b3 & 63;
                int v5 = ((b3 >> 6) & 3) | ((b4 & 15) << 2);
                int v6 = ((b4 >> 4) & 15) | ((b5 & 3) << 4);
                int v7 = (b5 >> 2) & 63;
                const float s = sc[g], moff = -31.0f * sc[g];
                half8 bf;
                bf[0] = (_Float16)fmaf((float)v0, s, moff);
                bf[1] = (_Float16)fmaf((float)v1, s, moff);
                bf[2] = (_Float16)fmaf((float)v2, s, moff);
                bf[3] = (_Float16)fmaf((float)v3, s, moff);
                bf[4] = (_Float16)fmaf((float)v4, s, moff);
                bf[5] = (_Float16)fmaf((float)v5, s, moff);
                bf[6] = (_Float16)fmaf((float)v6, s, moff);
                bf[7] = (_Float16)fmaf((float)v7, s, moff);
#pragma unroll
                for (int mt = 0; mt < 4; ++mt) {
                    half8 a = *(const half8*)&Ab[bi][mt][lane * 8];
                    acc[mt] = __builtin_amdgcn_mfma_f32_16x16x32_f16(a, bf, acc[mt], 0, 0, 0);
                }
            }
        }
#undef STAGE6
    } else {
        // ================= 5-bit region (chunk kc: k 1024*kc..+1024) =================
        const int klc   = kc - 1;                       // 0..2
        const int rbase = klc * 640;                    // packed-row base in Wl
        float sc[8];
#pragma unroll
        for (int g = 0; g < 8; ++g) sc[g] = sl[(klc * 8 + g) * NFEAT + n];

#define STAGE5(T) do {                                                         \
        const int _t = (T); const int _b = _t & 3;                             \
        const int* _gs = Wl + (rbase + _t * 20 + wave * 5) * NFEAT + n0 + lane;\
        GLOAD4(_gs,             &Wb[_b][(wave * 5 + 0) * 72]);                 \
        GLOAD4(_gs + 1 * NFEAT, &Wb[_b][(wave * 5 + 1) * 72]);                 \
        GLOAD4(_gs + 2 * NFEAT, &Wb[_b][(wave * 5 + 2) * 72]);                 \
        GLOAD4(_gs + 3 * NFEAT, &Wb[_b][(wave * 5 + 3) * 72]);                 \
        GLOAD4(_gs + 4 * NFEAT, &Wb[_b][(wave * 5 + 4) * 72]);                 \
        GLOAD16(xfrag + ((size_t)((kc * 32 + _t) * 4 + wave) * 64 + lane) * 8, \
                &Ab[_b][wave][0]);                                             \
    } while (0)

        STAGE5(0);
        STAGE5(1);
#pragma unroll
        for (int g = 0; g < 8; ++g) {
            for (int st = 0; st < 4; ++st) {
                const int t = g * 4 + st;
                if (t + 2 < 32) { STAGE5(t + 2); WAITV(12); }   // 2 batches x 6 in flight
                else if (t + 1 < 32) { WAITV(6); }
                else { WAITV(0); }
                __builtin_amdgcn_s_barrier();
                asm volatile("" ::: "memory");

                const int  bi = t & 3;
                const int* wr = &Wb[bi][(o * 5) * 72 + cb];
                const int b0 = wr[0]; const int b1 = wr[72];
                const int b2 = wr[2 * 72]; const int b3 = wr[3 * 72];
                const int b4 = wr[4 * 72];
                int v0 = b0 & 31;
                int v1 = ((b0 >> 5) & 7) | ((b1 & 3) << 3);
                int v2 = (b1 >> 2) & 31;
                int v3 = ((b1 >> 7) & 1) | ((b2 & 15) << 1);
                int v4 = ((b2 >> 4) & 15) | ((b3 & 1) << 4);
                int v5 = (b3 >> 1) & 31;
                int v6 = ((b3 >> 6) & 3) | ((b4 & 7) << 2);
                int v7 = (b4 >> 3) & 31;
                const float s = sc[g], moff = -15.0f * sc[g];
                half8 bf;
                bf[0] = (_Float16)fmaf((float)v0, s, moff);
                bf[1] = (_Float16)fmaf((float)v1, s, moff);
                bf[2] = (_Float16)fmaf((float)v2, s, moff);
                bf[3] = (_Float16)fmaf((float)v3, s, moff);
                bf[4] = (_Float16)fmaf((float)v4, s, moff);
                bf[5] = (_Float16)fmaf((float)v5, s, moff);
                bf[6] = (_Float16)fmaf((float)v6, s, moff);
                bf[7] = (_Float16)fmaf((float)v7, s, moff);
#pragma unroll
                for (int mt = 0; mt < 4; ++mt) {
                    half8 a = *(const half8*)&Ab[bi][mt][lane * 8];
                    acc[mt] = __builtin_amdgcn_mfma_f32_16x16x32_f16(a, bf, acc[mt], 0, 0, 0);
                }
            }
        }
#undef STAGE5
    }

    // ---- epilogue: waves own disjoint cols -> direct store ----
    // D row = mt*16 + (lane>>4)*4 + r, col = n
    const int r0 = (lane >> 4) << 2;
    if (atomic_mode) {
#pragma unroll
        for (int mt = 0; mt < 4; ++mt)
#pragma unroll
            for (int r = 0; r < 4; ++r)
                atomicAdd(&dst[(mt * 16 + r0 + r) * NFEAT + n], acc[mt][r]);
    } else {
        float* base = dst + (size_t)kc * 64 * NFEAT;
#pragma unroll
        for (int mt = 0; mt < 4; ++mt)
#pragma unroll
            for (int r = 0; r < 4; ++r)
                base[(mt * 16 + r0 + r) * NFEAT + n] = acc[mt][r];
    }
}

// ---------------- reduce: out = bias + sum_kc partial[kc] ----------------
__global__ __launch_bounds__(256) void reduce_out(const float* __restrict__ part,
                                                  const float* __restrict__ bias,
                                                  float* __restrict__ out, int nc) {
    const int idx = blockIdx.x * 256 + threadIdx.x;    // 0..176127 (float4 units)
    const int f   = idx * 4;
    const int n   = f % NFEAT;                          // NFEAT % 4 == 0 -> same row
    f32x4 sum = *(const f32x4*)(bias + n);
    for (int c = 0; c < nc; ++c)
        sum += *(const f32x4*)(part + (size_t)c * 704512 + f);
    *(f32x4*)(out + f) = sum;
}

__global__ __launch_bounds__(256) void init_bias(const float* __restrict__ bias,
                                                 float* __restrict__ out) {
    const int idx = blockIdx.x * 256 + threadIdx.x;    // 0..704511
    out[idx] = bias[idx % NFEAT];
}

extern "C" void kernel_launch(void* const* d_in, const int* in_sizes, int n_in,
                              void* d_out, int out_size, void* d_ws, size_t ws_size,
                              hipStream_t stream) {
    const float* x    = (const float*)d_in[0];
    const int*   Wh   = (const int*)d_in[1];
    const int*   Wl   = (const int*)d_in[2];
    const float* sh   = (const float*)d_in[3];
    const float* sl   = (const float*)d_in[4];
    const int*   col  = (const int*)d_in[5];
    const float* bias = (const float*)d_in[6];
    float* out = (float*)d_out;

    _Float16* xfrag = (_Float16*)d_ws;                 // 512 KB
    const size_t xo = 524288;
    const size_t part1 = 64ull * NFEAT * sizeof(float);         // 2.816 MB per chunk

    prep_xfrag<<<1024, 256, 0, stream>>>(x, col, xfrag);

    dim3 grid(172, 4);
    if (ws_size >= xo + 4 * part1) {
        float* part = (float*)((char*)d_ws + xo);
        gemm_kernel<<<grid, 256, 0, stream>>>(Wh, Wl, sh, sl, xfrag, part, 0);
        reduce_out<<<688, 256, 0, stream>>>(part, bias, out, 4);
    } else {
        init_bias<<<2752, 256, 0, stream>>>(bias, out);
        gemm_kernel<<<grid, 256, 0, stream>>>(Wh, Wl, sh, sl, xfrag, out, 1);
    }
}